// Round 1
// baseline (194.955 us; speedup 1.0000x reference)
//
#include <hip/hip_runtime.h>
#include <stdint.h>
#include <stddef.h>

typedef __bf16 bf16;
typedef bf16 bf16x4 __attribute__((ext_vector_type(4)));
typedef bf16 bf16x8 __attribute__((ext_vector_type(8)));
typedef float f32x4 __attribute__((ext_vector_type(4)));

#define MFMA16(a, b, c) __builtin_amdgcn_mfma_f32_16x16x32_bf16((a), (b), (c), 0, 0, 0)

// async global->LDS, 16B per lane, dest = wave-uniform base + lane*16
#define GLD_LDS16(g, l)                                          \
    __builtin_amdgcn_global_load_lds(                            \
        (const __attribute__((address_space(1))) void*)(g),      \
        (__attribute__((address_space(3))) void*)(l), 16, 0, 0)

// ---------------- f32 -> bf16 cast (weights) ----------------
__global__ __launch_bounds__(256) void cast_kernel(const float* __restrict__ in,
                                                   bf16* __restrict__ out) {
    int i = (blockIdx.x * 256 + threadIdx.x) * 4;
    float4 v = *(const float4*)(in + i);
    bf16x4 o;
    o[0] = (bf16)v.x; o[1] = (bf16)v.y; o[2] = (bf16)v.z; o[3] = (bf16)v.w;
    *(bf16x4*)(out + i) = o;
}

// ---------------- pos-add + LayerNorm + cast ----------------
__global__ __launch_bounds__(256) void posln_kernel(const float* __restrict__ x,
                                                    const float* __restrict__ pos,
                                                    const float* __restrict__ w,
                                                    const float* __restrict__ b,
                                                    bf16* __restrict__ out) {
    int row = blockIdx.x;
    int t = threadIdx.x;
    float4 v = ((const float4*)(x + (size_t)row * 1024))[t];
    if (pos != nullptr) {
        float4 p = ((const float4*)(pos + (size_t)row * 1024))[t];
        v.x += p.x; v.y += p.y; v.z += p.z; v.w += p.w;
    }
    float s1 = v.x + v.y + v.z + v.w;
    float s2 = v.x * v.x + v.y * v.y + v.z * v.z + v.w * v.w;
#pragma unroll
    for (int off = 1; off < 64; off <<= 1) {
        s1 += __shfl_xor(s1, off);
        s2 += __shfl_xor(s2, off);
    }
    __shared__ float red[8];
    int wave = t >> 6;
    if ((t & 63) == 0) { red[wave * 2] = s1; red[wave * 2 + 1] = s2; }
    __syncthreads();
    s1 = red[0] + red[2] + red[4] + red[6];
    s2 = red[1] + red[3] + red[5] + red[7];
    float mu = s1 * (1.0f / 1024.0f);
    float var = s2 * (1.0f / 1024.0f) - mu * mu;
    float rstd = rsqrtf(var + 1e-5f);
    float4 wv = ((const float4*)w)[t];
    float4 bv = ((const float4*)b)[t];
    bf16x4 o;
    o[0] = (bf16)((v.x - mu) * rstd * wv.x + bv.x);
    o[1] = (bf16)((v.y - mu) * rstd * wv.y + bv.y);
    o[2] = (bf16)((v.z - mu) * rstd * wv.z + bv.z);
    o[3] = (bf16)((v.w - mu) * rstd * wv.w + bv.w);
    *(bf16x4*)(out + (size_t)row * 1024 + t * 4) = o;
}

// ---------------- GEMM: out[M,1024] = A[M,1024] @ W^T, W row-major [N][K] ----------------
// 128x128 tile, BK=32, 4 waves each 64x64 (4x4 frags of 16x16x32 MFMA), m97 structure.
template <typename OutT, bool HasBias>
__global__ __launch_bounds__(256) void gemm_bt(const bf16* __restrict__ A,
                                               const bf16* __restrict__ w0,
                                               const bf16* __restrict__ w1,
                                               const bf16* __restrict__ w2,
                                               int rowsW0, int rowsW01,
                                               const float* __restrict__ bias,
                                               OutT* __restrict__ out) {
    __shared__ bf16 As[128 * 32];
    __shared__ bf16 Bs[128 * 32];
    int bx = blockIdx.x;
    int tileN = bx & 7;   // N = 1024 -> 8 tiles
    int tileM = bx >> 3;
    int t = threadIdx.x;
    int wave = t >> 6, lane = t & 63;
    int wr = wave >> 1, wc = wave & 1;
    int lr = lane & 15, lg = lane >> 4;
    int rowBase = tileM * 128;
    const bf16* W = (rowBase < rowsW0) ? w0 : ((rowBase < rowsW01) ? w1 : w2);
    const bf16* Ab = A + (size_t)rowBase * 1024;
    const bf16* Wb = W + (size_t)(tileN * 128) * 1024;

    // staging: 16B chunk index o16 = wave*128 + c*64 + lane; row=o16>>2, col=(o16&3)*8
    int o16a = wave * 128 + lane;
    int rowA0 = o16a >> 2, colA0 = (o16a & 3) * 8;
    int o16b = o16a + 64;
    int rowA1 = o16b >> 2, colA1 = (o16b & 3) * 8;

    const f32x4 zero4 = {0.f, 0.f, 0.f, 0.f};
    f32x4 acc[4][4];
#pragma unroll
    for (int i = 0; i < 4; ++i)
#pragma unroll
        for (int j = 0; j < 4; ++j) acc[i][j] = zero4;

    for (int k0 = 0; k0 < 1024; k0 += 32) {
        GLD_LDS16(Ab + (size_t)rowA0 * 1024 + k0 + colA0, (char*)As + wave * 2048);
        GLD_LDS16(Ab + (size_t)rowA1 * 1024 + k0 + colA1, (char*)As + wave * 2048 + 1024);
        GLD_LDS16(Wb + (size_t)rowA0 * 1024 + k0 + colA0, (char*)Bs + wave * 2048);
        GLD_LDS16(Wb + (size_t)rowA1 * 1024 + k0 + colA1, (char*)Bs + wave * 2048 + 1024);
        __syncthreads();
        bf16x8 af[4], bfr[4];
#pragma unroll
        for (int mf = 0; mf < 4; ++mf)
            af[mf] = *(const bf16x8*)((const char*)As + (wr * 64 + mf * 16 + lr) * 64 + lg * 16);
#pragma unroll
        for (int nf = 0; nf < 4; ++nf)
            bfr[nf] = *(const bf16x8*)((const char*)Bs + (wc * 64 + nf * 16 + lr) * 64 + lg * 16);
#pragma unroll
        for (int mf = 0; mf < 4; ++mf)
#pragma unroll
            for (int nf = 0; nf < 4; ++nf)
                acc[mf][nf] = MFMA16(af[mf], bfr[nf], acc[mf][nf]);
        __syncthreads();
    }
    // epilogue: C[row=(lg*4+r), col=lr] per 16x16 frag (m89-verified layout)
#pragma unroll
    for (int nf = 0; nf < 4; ++nf) {
        int ncol = tileN * 128 + wc * 64 + nf * 16 + lr;
        float bv = HasBias ? bias[ncol] : 0.0f;
#pragma unroll
        for (int mf = 0; mf < 4; ++mf) {
            int mrow = rowBase + wr * 64 + mf * 16 + lg * 4;
#pragma unroll
            for (int r = 0; r < 4; ++r) {
                float val = acc[mf][nf][r] + bv;
                out[(size_t)(mrow + r) * 1024 + ncol] = (OutT)val;
            }
        }
    }
}

// ---------------- flash attention ----------------
// qkv: [10240][1024] bf16; rows 0..2047 q4, 2048..6143 k4, 6144..10239 v4.
// block = (b,h,qtile of 64 rows); 4 waves x 16 q-rows; K-tiles of 32.
__global__ __launch_bounds__(256) void attn_kernel(const bf16* __restrict__ qkv,
                                                   const int* __restrict__ mask,
                                                   bf16* __restrict__ out) {
    __shared__ float bias_s[2048];
    __shared__ bf16 Ks[32 * 64];
    __shared__ bf16 Vs[32 * 64];
    __shared__ bf16 Ps[4][16 * 32];
    int bx = blockIdx.x;
    int qt = bx & 15, h = (bx >> 4) & 15, b = bx >> 8;
    int t = threadIdx.x;
    int wave = t >> 6, lane = t & 63, lr = lane & 15, lg = lane >> 4;

    const int* mrow = mask + b * 2048;
    for (int i = t; i < 2048; i += 256) bias_s[i] = mrow[i] ? -1e30f : 0.0f;

    int qrow = qt * 64 + wave * 16 + lr;
    const bf16* qptr = qkv + ((size_t)(b * 1024 + qrow)) * 1024 + h * 64;
    bf16x8 qf0 = *(const bf16x8*)(qptr + lg * 8);        // d = lg*8+j
    bf16x8 qf1 = *(const bf16x8*)(qptr + 32 + lg * 8);   // d = 32+lg*8+j

    const bf16* kbase = qkv + (size_t)2048 * 1024 + (size_t)(b * 2048) * 1024 + h * 64;
    const bf16* vbase = qkv + (size_t)6144 * 1024 + (size_t)(b * 2048) * 1024 + h * 64;

    const f32x4 zero4 = {0.f, 0.f, 0.f, 0.f};
    f32x4 accO[4];
#pragma unroll
    for (int d = 0; d < 4; ++d) accO[d] = zero4;
    float m_run = -1e30f, l_run = 0.0f;

    int o16 = wave * 64 + lane;       // K/V staging chunk
    int krow = o16 >> 3;
    int kcol = (o16 & 7) * 8;

    for (int kb = 0; kb < 2048; kb += 32) {
        GLD_LDS16(kbase + (size_t)(kb + krow) * 1024 + kcol, (char*)Ks + wave * 1024);
        GLD_LDS16(vbase + (size_t)(kb + krow) * 1024 + kcol, (char*)Vs + wave * 1024);
        __syncthreads();

        // swapped S = K·Q^T : C[key_local][q], key_local = lg*4+r (+16m), q = lr
        float sv[8];
        float mtile = -3e38f;
#pragma unroll
        for (int m = 0; m < 2; ++m) {
            bf16x8 kf0 = *(const bf16x8*)((const char*)Ks + (m * 16 + lr) * 128 + lg * 16);
            bf16x8 kf1 = *(const bf16x8*)((const char*)Ks + (m * 16 + lr) * 128 + 64 + lg * 16);
            f32x4 s = zero4;
            s = MFMA16(kf0, qf0, s);
            s = MFMA16(kf1, qf1, s);
#pragma unroll
            for (int r = 0; r < 4; ++r) {
                int key = kb + m * 16 + lg * 4 + r;
                float xsc = s[r] * 0.125f + bias_s[key];
                sv[m * 4 + r] = xsc;
                mtile = fmaxf(mtile, xsc);
            }
        }
        mtile = fmaxf(mtile, __shfl_xor(mtile, 16));
        mtile = fmaxf(mtile, __shfl_xor(mtile, 32));
        float mnew = fmaxf(m_run, mtile);
        float alpha = __expf(m_run - mnew);
        m_run = mnew;
        float lt = 0.f;
        float p[8];
#pragma unroll
        for (int i = 0; i < 8; ++i) { p[i] = __expf(sv[i] - mnew); lt += p[i]; }
        lt += __shfl_xor(lt, 16);
        lt += __shfl_xor(lt, 32);
        l_run = l_run * alpha + lt;

        // P -> per-wave LDS [16 q][32 k] for A-fragment re-layout
        bf16* pw = &Ps[wave][0];
#pragma unroll
        for (int m = 0; m < 2; ++m) {
            bf16x4 pk;
            pk[0] = (bf16)p[m * 4 + 0]; pk[1] = (bf16)p[m * 4 + 1];
            pk[2] = (bf16)p[m * 4 + 2]; pk[3] = (bf16)p[m * 4 + 3];
            *(bf16x4*)(pw + lr * 32 + m * 16 + lg * 4) = pk;
        }
        // rescale O (O rows are q = lg*4+r -> fetch that q's alpha)
        float af0 = __shfl(alpha, lg * 4 + 0);
        float af1 = __shfl(alpha, lg * 4 + 1);
        float af2 = __shfl(alpha, lg * 4 + 2);
        float af3 = __shfl(alpha, lg * 4 + 3);
#pragma unroll
        for (int d = 0; d < 4; ++d) {
            accO[d][0] *= af0; accO[d][1] *= af1;
            accO[d][2] *= af2; accO[d][3] *= af3;
        }
        // PV: A = P^T [16 q][32 k], B = V [32 k][16 d-block]
        bf16x8 pf = *(const bf16x8*)(pw + lr * 32 + lg * 8);
#pragma unroll
        for (int d = 0; d < 4; ++d) {
            bf16x8 vf;
#pragma unroll
            for (int j = 0; j < 8; ++j) vf[j] = Vs[(lg * 8 + j) * 64 + d * 16 + lr];
            accO[d] = MFMA16(pf, vf, accO[d]);
        }
        __syncthreads();
    }
    float li[4];
#pragma unroll
    for (int r = 0; r < 4; ++r) li[r] = 1.0f / __shfl(l_run, lg * 4 + r);
    bf16* ob = out + ((size_t)(b * 1024 + qt * 64 + wave * 16 + lg * 4)) * 1024 + h * 64 + lr;
#pragma unroll
    for (int d = 0; d < 4; ++d)
#pragma unroll
        for (int r = 0; r < 4; ++r)
            ob[(size_t)r * 1024 + d * 16] = (bf16)(accO[d][r] * li[r]);
}

extern "C" void kernel_launch(void* const* d_in, const int* in_sizes, int n_in,
                              void* d_out, int out_size, void* d_ws, size_t ws_size,
                              hipStream_t stream) {
    const float* q    = (const float*)d_in[0];
    const float* k    = (const float*)d_in[1];
    const float* v    = (const float*)d_in[2];
    const float* qpos = (const float*)d_in[3];
    const float* kpos = (const float*)d_in[4];
    const int*   mask = (const int*)d_in[5];
    const float* lnqw = (const float*)d_in[6];
    const float* lnqb = (const float*)d_in[7];
    const float* lnkw = (const float*)d_in[8];
    const float* lnkb = (const float*)d_in[9];
    const float* lnvw = (const float*)d_in[10];
    const float* lnvb = (const float*)d_in[11];
    const float* wq   = (const float*)d_in[12];
    const float* wk   = (const float*)d_in[13];
    const float* wv   = (const float*)d_in[14];
    const float* wp   = (const float*)d_in[15];
    const float* bp   = (const float*)d_in[16];
    float* out = (float*)d_out;

    char* ws = (char*)d_ws;
    const size_t MB = 1024 * 1024;
    bf16* wq_b = (bf16*)(ws + 0 * 2 * MB);
    bf16* wk_b = (bf16*)(ws + 1 * 2 * MB);
    bf16* wv_b = (bf16*)(ws + 2 * 2 * MB);
    bf16* wp_b = (bf16*)(ws + 3 * 2 * MB);
    bf16* xn   = (bf16*)(ws + 8 * MB);    // [10240][1024] bf16 (qn,kn,vn)
    bf16* qkv4 = (bf16*)(ws + 28 * MB);   // [10240][1024] bf16 (q4,k4,v4)
    bf16* attn = (bf16*)(ws + 48 * MB);   // [2048][1024]  bf16

    cast_kernel<<<1024, 256, 0, stream>>>(wq, wq_b);
    cast_kernel<<<1024, 256, 0, stream>>>(wk, wk_b);
    cast_kernel<<<1024, 256, 0, stream>>>(wv, wv_b);
    cast_kernel<<<1024, 256, 0, stream>>>(wp, wp_b);

    posln_kernel<<<2048, 256, 0, stream>>>(q, qpos, lnqw, lnqb, xn);
    posln_kernel<<<4096, 256, 0, stream>>>(k, kpos, lnkw, lnkb, xn + (size_t)2048 * 1024);
    posln_kernel<<<4096, 256, 0, stream>>>(v, nullptr, lnvw, lnvb, xn + (size_t)6144 * 1024);

    // batched QKV projection: rows 0..2047 -> w_q, 2048..6143 -> w_k, 6144..10239 -> w_v
    gemm_bt<bf16, false><<<640, 256, 0, stream>>>(xn, wq_b, wk_b, wv_b, 2048, 6144,
                                                  nullptr, qkv4);

    attn_kernel<<<512, 256, 0, stream>>>(qkv4, mask, attn);

    // output projection (+bias), f32 out
    gemm_bt<float, true><<<128, 256, 0, stream>>>(attn, wp_b, wp_b, wp_b, 1 << 20, 1 << 20,
                                                  bp, out);
}